// Round 5
// baseline (1137.709 us; speedup 1.0000x reference)
//
#include <hip/hip_runtime.h>

// LowBitMLP on MI355X (gfx950).
// R7 = R6 resubmit (previous round died to an infra container failure; code
// re-audited: uniform barriers, vm ledger verified, no host-API hazards).
// R6: (a) per-GEMM swizzle: OFF for GEMM1 (R5 measured harm: 350->375us,
//     FETCH 197->542MB; natural raster already gives 8rowx4col/XCD
//     residency), ON for GEMM2 (gx=8 => xcd==bx pathology, A refetched 8x).
// (b) late vm gates: move VMC4 from {stage;VMC4;bar;MFMA} to
//     {stage;bar;MFMA;VMC4;bar}. Ledger-identical (no vm ops between MFMA
//     and gate => same queue; protected ds_reads still strictly after
//     gate+barrier), but the ~620cyc MFMA section now runs UNDER the vm
//     latency instead of after it. 2 gates/K-tile.
// (c) stage issue at top of each phase (before ds_reads): loads start
//     ~300cyc earlier, vm op order unchanged.
// Ledger (steady state, tile t, buf cur = t&1, nx = cur^1):
//   vm issue order: A(t+1,k0)@P0, B(t+1,k0)@P1, A(t+1,k1)@P2, B(t+1,k1)@P3.
//   gate @P1 (after MFMA): outstanding {A(t,k1),B(t,k1),A(t+1,k0),B(t+1,k0)}
//     = 8; vmcnt(4) certifies A/B(t,k1) -> P2 reads kh1(t) safe.
//   gate @P3 (after MFMA): outstanding {A/B(t+1,k0),A/B(t+1,k1)} = 8;
//     vmcnt(4) certifies A/B(t+1,k0) -> P0(t+1) reads safe.
//   Tail (t=nT-1): P1 else-branch VMC0 drains last 4 ops before P2 reads.
//   WAR: each staged region's last reader finished >=2 barriers before issue.
//
// Memory plan (unchanged):
//   d_out: [0,32M) x_h f16; [32M,64M) tw1 f16   (dead before GEMM2 writes)
//   d_ws : [0,32M) tw2 f16; [32M,160M) h f16 (GEMM1 out, LN1+relu in place)

#define THRESH 0.1f
#define LN_EPS 1e-5f

typedef _Float16 f16x8 __attribute__((ext_vector_type(8)));
typedef float f32x4 __attribute__((ext_vector_type(4)));

typedef __attribute__((address_space(3))) void lds_void;
typedef const __attribute__((address_space(1))) void glob_void;

__device__ __forceinline__ void gld16(const void* g, void* l) {
  __builtin_amdgcn_global_load_lds((glob_void*)g, (lds_void*)l, 16, 0, 0);
}

// ---------------- elementwise prep ----------------

__global__ __launch_bounds__(256) void cvt_x_f16(const float* __restrict__ x,
                                                 _Float16* __restrict__ y) {
  const long i = ((long)blockIdx.x * 256 + threadIdx.x) * 8;
  const float4 v0 = *(const float4*)(x + i);
  const float4 v1 = *(const float4*)(x + i + 4);
  const float a[8] = {v0.x, v0.y, v0.z, v0.w, v1.x, v1.y, v1.z, v1.w};
  f16x8 o;
#pragma unroll
  for (int e = 0; e < 8; ++e) o[e] = (_Float16)a[e];
  *(f16x8*)(y + i) = o;
}

__global__ __launch_bounds__(256) void quant_w(const float* __restrict__ w,
                                               _Float16* __restrict__ t) {
  const long i = ((long)blockIdx.x * 256 + threadIdx.x) * 8;
  const float4 v0 = *(const float4*)(w + i);
  const float4 v1 = *(const float4*)(w + i + 4);
  const float a[8] = {v0.x, v0.y, v0.z, v0.w, v1.x, v1.y, v1.z, v1.w};
  f16x8 o;
#pragma unroll
  for (int e = 0; e < 8; ++e) {
    const float q = (fabsf(a[e]) < THRESH) ? 0.f : (a[e] > 0.f ? 1.f : -1.f);
    o[e] = (_Float16)q;
  }
  *(f16x8*)(t + i) = o;
}

// ---------------- 256^2 8-phase GEMM-BT: C = A(MxK) * B(NxK)^T, fused (acc+b)*s --------
// LDS layout: per buffer, per k-half, 16 fragment blocks of 16rows x 32k
// (1KB each, fragment-contiguous => conflict-free ds_read_b128; staging dest
// is linear chunk index => satisfies global_load_lds wave-uniform+lane*16).

#define BARF()                       \
  __builtin_amdgcn_s_barrier();      \
  asm volatile("" ::: "memory")
#define VMC4() asm volatile("s_waitcnt vmcnt(4)" ::: "memory")
#define VMC0() asm volatile("s_waitcnt vmcnt(0)" ::: "memory")

#define MFMA_QUAD(m0, AF)                                                                    \
  __builtin_amdgcn_s_setprio(1);                                                             \
  _Pragma("unroll") for (int i = 0; i < 4; ++i)                                              \
  _Pragma("unroll") for (int j = 0; j < 4; ++j)                                              \
      acc[(m0) + i][j] = __builtin_amdgcn_mfma_f32_16x16x32_f16(AF[i], bf[j],                \
                                                                acc[(m0) + i][j], 0, 0, 0); \
  __builtin_amdgcn_s_setprio(0)

template <bool OUT_F16, bool SWZ>
__global__ __launch_bounds__(512, 2) void gemm256(const _Float16* __restrict__ A,
                                                  const _Float16* __restrict__ B,
                                                  void* __restrict__ C,
                                                  const float* __restrict__ bias,
                                                  const float* __restrict__ scale,
                                                  int N, int K) {
  __shared__ _Float16 sA[2][2][8192];  // [buf][khalf][16 frag * 512] = 64KB
  __shared__ _Float16 sB[2][2][8192];  // 64KB

  const int tid = threadIdx.x;
  const int lane = tid & 63;
  const int wave = tid >> 6;
  const int wm = wave >> 2;  // 0..1 -> C rows wm*128..+128
  const int wn = wave & 3;   // 0..3 -> C cols wn*64..+64

  // T1 chunked XCD swizzle, per-GEMM. GEMM2 (gx=8): natural order puts the
  // whole column on one XCD (xcd = hw%8 = bx) => A fetched 8x. Chunking gives
  // each XCD 4 rows x 8 cols. GEMM1 (gx=32): natural already near-optimal
  // (R5 A/B: swizzle cost +25us, fetch 197->542MB) => SWZ=false.
  int bx, by;
  if constexpr (SWZ) {
    const int gx = gridDim.x;
    const int nwg = gx * gridDim.y;
    const int hw = blockIdx.y * gx + blockIdx.x;
    const int logical = (hw & 7) * (nwg >> 3) + (hw >> 3);
    bx = logical % gx;
    by = logical / gx;
  } else {
    bx = blockIdx.x;
    by = blockIdx.y;
  }
  const long row0 = (long)by * 256;
  const long col0 = (long)bx * 256;

  // Staging: chunk c in [0,1024): frag mb=c>>6, row=mb*16+(c&15), koct=(c>>4)&3.
  const int c0 = tid, c1 = tid + 512;
  const _Float16* pA0 = A + (row0 + ((c0 >> 6) << 4) + (c0 & 15)) * (long)K + (((c0 >> 4) & 3) << 3);
  const _Float16* pA1 = A + (row0 + ((c1 >> 6) << 4) + (c1 & 15)) * (long)K + (((c1 >> 4) & 3) << 3);
  const _Float16* pB0 = B + (col0 + ((c0 >> 6) << 4) + (c0 & 15)) * (long)K + (((c0 >> 4) & 3) << 3);
  const _Float16* pB1 = B + (col0 + ((c1 >> 6) << 4) + (c1 & 15)) * (long)K + (((c1 >> 4) & 3) << 3);

#define STG_A(nx, kh, koff)                     \
  gld16(pA0 + (koff), &sA[nx][kh][c0 * 8]);     \
  gld16(pA1 + (koff), &sA[nx][kh][c1 * 8])
#define STG_B(nx, kh, koff)                     \
  gld16(pB0 + (koff), &sB[nx][kh][c0 * 8]);     \
  gld16(pB1 + (koff), &sB[nx][kh][c1 * 8])

  f32x4 acc[8][4] = {};
  const int nT = K >> 6;
  const int aoff = wm * 8 * 512 + lane * 8;  // elems; frag mf adds mf*512
  const int boff = wn * 4 * 512 + lane * 8;

  // Prologue: tile 0 -> buf 0; certify kh0 (leaves A/B(0,k1) outstanding).
  STG_A(0, 0, 0);
  STG_B(0, 0, 0);
  STG_A(0, 1, 32);
  STG_B(0, 1, 32);
  VMC4();
  BARF();

  for (int t = 0; t < nT; ++t) {
    const int cur = t & 1, nx = cur ^ 1;
    const bool more1 = (t + 1 < nT);
    const int kn1 = (t + 1) << 6;  // elems along K for tile t+1

    f16x8 af[4], af2[4], bf[4];

    // ---- P0: stage A(t+1,k0); issue ALL kh0 reads (af0-3, bf, af4-7) ----
    if (more1) { STG_A(nx, 0, kn1); }
#pragma unroll
    for (int i = 0; i < 4; ++i) af[i] = *(const f16x8*)&sA[cur][0][aoff + i * 512];
#pragma unroll
    for (int j = 0; j < 4; ++j) bf[j] = *(const f16x8*)&sB[cur][0][boff + j * 512];
#pragma unroll
    for (int i = 0; i < 4; ++i) af2[i] = *(const f16x8*)&sA[cur][0][aoff + (4 + i) * 512];
    BARF();
    MFMA_QUAD(0, af);  // compiler emits counted lgkmcnt: af2 still in flight
    BARF();

    // ---- P1: stage B(t+1,k0); MFMA kh0 m4-7; LATE gate kh1(t) ----
    if (more1) { STG_B(nx, 0, kn1); }
    BARF();
    MFMA_QUAD(4, af2);
    if (more1) {
      VMC4();  // A/B(t,k1) landed; newer = A/B(t+1,k0). MFMA ran under wait.
    } else {
      VMC0();  // last tile: only A/B(t,k1) outstanding
    }
    BARF();

    // ---- P2: stage A(t+1,k1); issue ALL kh1 reads ----
    if (more1) { STG_A(nx, 1, kn1 + 32); }
#pragma unroll
    for (int i = 0; i < 4; ++i) af[i] = *(const f16x8*)&sA[cur][1][aoff + i * 512];
#pragma unroll
    for (int j = 0; j < 4; ++j) bf[j] = *(const f16x8*)&sB[cur][1][boff + j * 512];
#pragma unroll
    for (int i = 0; i < 4; ++i) af2[i] = *(const f16x8*)&sA[cur][1][aoff + (4 + i) * 512];
    BARF();
    MFMA_QUAD(0, af);
    BARF();

    // ---- P3: stage B(t+1,k1); MFMA kh1 m4-7; LATE gate kh0(t+1) ----
    if (more1) { STG_B(nx, 1, kn1 + 32); }
    BARF();
    MFMA_QUAD(4, af2);
    if (more1) {
      VMC4();  // A/B(t+1,k0) landed; newer = A/B(t+1,k1)
    }
    BARF();
  }

  // Epilogue: C/D layout col = lane&15, row = (lane>>4)*4 + reg.
  const int qd = lane >> 4, l16 = lane & 15;
#pragma unroll
  for (int nf = 0; nf < 4; ++nf) {
    const long c = col0 + wn * 64 + nf * 16 + l16;
    const float bb = bias[c];
    const float ss = scale[c];
#pragma unroll
    for (int mf = 0; mf < 8; ++mf) {
      const long r = row0 + wm * 128 + mf * 16 + qd * 4;
#pragma unroll
      for (int reg = 0; reg < 4; ++reg) {
        const float v = (acc[mf][nf][reg] + bb) * ss;
        if constexpr (OUT_F16)
          ((_Float16*)C)[(r + reg) * (long)N + c] = (_Float16)v;
        else
          ((float*)C)[(r + reg) * (long)N + c] = v;
      }
    }
  }
}

// ---------------- row LayerNorm kernels ----------------

// D = 8192, f16 in/out, LN*g+b then relu, in place. One block (256 thr) per row.
__global__ __launch_bounds__(256) void ln_relu_rows_f16(_Float16* __restrict__ h,
                                                        const float* __restrict__ g,
                                                        const float* __restrict__ b) {
  const int D = 8192;
  const long base = (long)blockIdx.x * D;
  const int tid = threadIdx.x;
  f16x8 v[4];
  float sum = 0.f, sq = 0.f;
#pragma unroll
  for (int c = 0; c < 4; ++c) {
    v[c] = *(const f16x8*)&h[base + c * 2048 + tid * 8];
#pragma unroll
    for (int e = 0; e < 8; ++e) {
      const float f = (float)v[c][e];
      sum += f;
      sq += f * f;
    }
  }
#pragma unroll
  for (int off = 32; off > 0; off >>= 1) {
    sum += __shfl_down(sum, off);
    sq += __shfl_down(sq, off);
  }
  __shared__ float rs[4], rq[4];
  const int wv = tid >> 6, ln = tid & 63;
  if (ln == 0) { rs[wv] = sum; rq[wv] = sq; }
  __syncthreads();
  sum = rs[0] + rs[1] + rs[2] + rs[3];
  sq = rq[0] + rq[1] + rq[2] + rq[3];
  const float mu = sum / D;
  const float rstd = rsqrtf(sq / D - mu * mu + LN_EPS);
#pragma unroll
  for (int c = 0; c < 4; ++c) {
    const int col = c * 2048 + tid * 8;
    f16x8 o;
#pragma unroll
    for (int e = 0; e < 8; ++e) {
      const float f = ((float)v[c][e] - mu) * rstd * g[col + e] + b[col + e];
      o[e] = (_Float16)fmaxf(f, 0.f);
    }
    *(f16x8*)&h[base + col] = o;
  }
}

// D = 2048, f32, LN*g+b IN PLACE on d_out. One block (256 thr) per row.
__global__ __launch_bounds__(256) void ln_rows_f32_inplace(float* __restrict__ io,
                                                           const float* __restrict__ g,
                                                           const float* __restrict__ b) {
  const int D = 2048;
  const long base = (long)blockIdx.x * D;
  const int tid = threadIdx.x;
  const float4 v0 = *(const float4*)&io[base + tid * 8];
  const float4 v1 = *(const float4*)&io[base + tid * 8 + 4];
  const float a[8] = {v0.x, v0.y, v0.z, v0.w, v1.x, v1.y, v1.z, v1.w};
  float sum = 0.f, sq = 0.f;
#pragma unroll
  for (int e = 0; e < 8; ++e) {
    sum += a[e];
    sq += a[e] * a[e];
  }
#pragma unroll
  for (int off = 32; off > 0; off >>= 1) {
    sum += __shfl_down(sum, off);
    sq += __shfl_down(sq, off);
  }
  __shared__ float rs[4], rq[4];
  const int wv = tid >> 6, ln = tid & 63;
  if (ln == 0) { rs[wv] = sum; rq[wv] = sq; }
  __syncthreads();
  sum = rs[0] + rs[1] + rs[2] + rs[3];
  sq = rq[0] + rq[1] + rq[2] + rq[3];
  const float mu = sum / D;
  const float rstd = rsqrtf(sq / D - mu * mu + LN_EPS);
  const int col = tid * 8;
  float o[8];
#pragma unroll
  for (int e = 0; e < 8; ++e) o[e] = (a[e] - mu) * rstd * g[col + e] + b[col + e];
  *(float4*)&io[base + col] = make_float4(o[0], o[1], o[2], o[3]);
  *(float4*)&io[base + col + 4] = make_float4(o[4], o[5], o[6], o[7]);
}

// ---------------- launch ----------------

extern "C" void kernel_launch(void* const* d_in, const int* in_sizes, int n_in,
                              void* d_out, int out_size, void* d_ws, size_t ws_size,
                              hipStream_t stream) {
  const float* x    = (const float*)d_in[0];
  const float* w1   = (const float*)d_in[1];
  const float* b1   = (const float*)d_in[2];
  const float* s1   = (const float*)d_in[3];
  const float* w2   = (const float*)d_in[4];
  const float* b2   = (const float*)d_in[5];
  const float* s2   = (const float*)d_in[6];
  const float* ln1g = (const float*)d_in[7];
  const float* ln1b = (const float*)d_in[8];
  const float* outg = (const float*)d_in[9];
  const float* outb = (const float*)d_in[10];

  const int N = 8192, D_IN = 2048, D_H = 8192, D_OUT = 2048;
  const size_t MB = 1024 * 1024;
  // Scratch phase-1 buffers live in d_out (64MB); dead before GEMM2 writes it.
  char* ob = (char*)d_out;
  _Float16* xh  = (_Float16*)(ob);            // 32MB
  _Float16* tw1 = (_Float16*)(ob + 32 * MB);  // 32MB
  // Persistent-through-GEMM2 buffers in d_ws (160MB used).
  char* ws = (char*)d_ws;
  _Float16* tw2 = (_Float16*)(ws);            // 32MB
  _Float16* h   = (_Float16*)(ws + 32 * MB);  // 128MB

  // elementwise prep: each block handles 2048 elems
  cvt_x_f16<<<(N * D_IN) / 2048, 256, 0, stream>>>(x, xh);
  quant_w<<<(D_H * D_IN) / 2048, 256, 0, stream>>>(w1, tw1);
  quant_w<<<(D_OUT * D_H) / 2048, 256, 0, stream>>>(w2, tw2);

  // layer 1: h = (x @ tw1^T + b1) * s1   -> f16  (no swizzle: natural raster wins)
  gemm256<true, false><<<dim3(D_H / 256, N / 256), 512, 0, stream>>>(xh, tw1, h, b1, s1, D_H, D_IN);
  // LN + relu in place
  ln_relu_rows_f16<<<N, 256, 0, stream>>>(h, ln1g, ln1b);

  // layer 2: (h @ tw2^T + b2) * s2 -> f32, straight into d_out (xh/tw1 dead)
  // swizzle ON: gx=8 natural order puts each column on one XCD (A refetch 8x)
  gemm256<false, true><<<dim3(D_OUT / 256, N / 256), 512, 0, stream>>>(h, tw2, d_out, b2, s2, D_OUT, D_H);
  // final LN in place on d_out
  ln_rows_f32_inplace<<<N, 256, 0, stream>>>((float*)d_out, outg, outb);
}

// Round 6
// 972.060 us; speedup vs baseline: 1.1704x; 1.1704x over previous
//
#include <hip/hip_runtime.h>

// LowBitMLP on MI355X (gfx950).
// R8: consolidate to best-measured combo + static-buffer unroll.
//   - EARLY gates (R3/R5 placement). R7 measured late gates: G1 350->495us,
//     MfmaUtil 23.5% => all-wave lockstep exposure of vm latency. Reverted.
//   - Per-GEMM swizzle: OFF for G1 (R5: swizzle cost +25us, FETCH 197->542MB),
//     ON for G2 (R4: natural order => xcd==bx, A refetched 8x, FETCH 1.05GB).
//   - NEW: K-loop unrolled x2 => cur/nx compile-time => LDS addresses become
//     base VGPR + immediate offsets (cuts VALU addr calc; VALUBusy 12-16%).
// Ledger (verified R3/R5; steady state, tile t, buf cur, nx=cur^1):
//   vm issue order: A(t+1,k0)@P0, B(t+1,k0)@P1, A(t+1,k1)@P2, B(t+1,k1)@P3.
//   gate @P1 (after STG_B, BEFORE barrier): outstanding {A/B(t,k1),
//     A/B(t+1,k0)} = 8; vmcnt(4) certifies A/B(t,k1) -> P2 reads safe.
//   gate @P3: outstanding {A/B(t+1,k0), A/B(t+1,k1)} = 8; vmcnt(4)
//     certifies A/B(t+1,k0) -> P0(t+1) reads safe.
//   Tail (t=nT-1): P1 VMC0 drains the last 4 ops before P2 reads; no stages.
//   WAR: each staged region's last reader finished >=2 barriers before issue.
//
// Memory plan (unchanged):
//   d_out: [0,32M) x_h f16; [32M,64M) tw1 f16   (dead before GEMM2 writes)
//   d_ws : [0,32M) tw2 f16; [32M,160M) h f16 (GEMM1 out, LN1+relu in place)

#define THRESH 0.1f
#define LN_EPS 1e-5f

typedef _Float16 f16x8 __attribute__((ext_vector_type(8)));
typedef float f32x4 __attribute__((ext_vector_type(4)));

typedef __attribute__((address_space(3))) void lds_void;
typedef const __attribute__((address_space(1))) void glob_void;

__device__ __forceinline__ void gld16(const void* g, void* l) {
  __builtin_amdgcn_global_load_lds((glob_void*)g, (lds_void*)l, 16, 0, 0);
}

// ---------------- elementwise prep ----------------

__global__ __launch_bounds__(256) void cvt_x_f16(const float* __restrict__ x,
                                                 _Float16* __restrict__ y) {
  const long i = ((long)blockIdx.x * 256 + threadIdx.x) * 8;
  const float4 v0 = *(const float4*)(x + i);
  const float4 v1 = *(const float4*)(x + i + 4);
  const float a[8] = {v0.x, v0.y, v0.z, v0.w, v1.x, v1.y, v1.z, v1.w};
  f16x8 o;
#pragma unroll
  for (int e = 0; e < 8; ++e) o[e] = (_Float16)a[e];
  *(f16x8*)(y + i) = o;
}

__global__ __launch_bounds__(256) void quant_w(const float* __restrict__ w,
                                               _Float16* __restrict__ t) {
  const long i = ((long)blockIdx.x * 256 + threadIdx.x) * 8;
  const float4 v0 = *(const float4*)(w + i);
  const float4 v1 = *(const float4*)(w + i + 4);
  const float a[8] = {v0.x, v0.y, v0.z, v0.w, v1.x, v1.y, v1.z, v1.w};
  f16x8 o;
#pragma unroll
  for (int e = 0; e < 8; ++e) {
    const float q = (fabsf(a[e]) < THRESH) ? 0.f : (a[e] > 0.f ? 1.f : -1.f);
    o[e] = (_Float16)q;
  }
  *(f16x8*)(t + i) = o;
}

// ---------------- 256^2 8-phase GEMM-BT: C = A(MxK) * B(NxK)^T, fused (acc+b)*s --------
// LDS layout: per buffer, per k-half, 16 fragment blocks of 16rows x 32k
// (1KB each, fragment-contiguous => conflict-free ds_read_b128; staging dest
// is linear chunk index => satisfies global_load_lds wave-uniform+lane*16).

#define BARF()                       \
  __builtin_amdgcn_s_barrier();      \
  asm volatile("" ::: "memory")
#define VMC4() asm volatile("s_waitcnt vmcnt(4)" ::: "memory")
#define VMC0() asm volatile("s_waitcnt vmcnt(0)" ::: "memory")

#define MFMA_QUAD(m0, AF)                                                                    \
  __builtin_amdgcn_s_setprio(1);                                                             \
  _Pragma("unroll") for (int i = 0; i < 4; ++i)                                              \
  _Pragma("unroll") for (int j = 0; j < 4; ++j)                                              \
      acc[(m0) + i][j] = __builtin_amdgcn_mfma_f32_16x16x32_f16(AF[i], bf[j],                \
                                                                acc[(m0) + i][j], 0, 0, 0); \
  __builtin_amdgcn_s_setprio(0)

#define STG_A(nx, kh, koff)                     \
  gld16(pA0 + (koff), &sA[nx][kh][c0 * 8]);     \
  gld16(pA1 + (koff), &sA[nx][kh][c1 * 8])
#define STG_B(nx, kh, koff)                     \
  gld16(pB0 + (koff), &sB[nx][kh][c0 * 8]);     \
  gld16(pB1 + (koff), &sB[nx][kh][c1 * 8])

// One K-tile, 4 phases, CUR/NX compile-time. Reads-then-stage, EARLY gates.
#define TILE_BODY(CUR, NX, TT)                                                  \
  {                                                                             \
    const bool more1 = ((TT) + 1 < nT);                                         \
    const int kn1 = ((TT) + 1) << 6;                                            \
    f16x8 af[4], af2[4], bf[4];                                                 \
    /* P0: all kh0 reads; stage A(t+1,k0) */                                    \
    _Pragma("unroll") for (int i = 0; i < 4; ++i)                               \
        af[i] = *(const f16x8*)&sA[CUR][0][aoff + i * 512];                     \
    _Pragma("unroll") for (int j = 0; j < 4; ++j)                               \
        bf[j] = *(const f16x8*)&sB[CUR][0][boff + j * 512];                     \
    _Pragma("unroll") for (int i = 0; i < 4; ++i)                               \
        af2[i] = *(const f16x8*)&sA[CUR][0][aoff + (4 + i) * 512];              \
    if (more1) { STG_A(NX, 0, kn1); }                                           \
    BARF();                                                                     \
    MFMA_QUAD(0, af);                                                           \
    BARF();                                                                     \
    /* P1: stage B(t+1,k0); EARLY gate kh1(t); MFMA kh0 m4-7 */                 \
    if (more1) {                                                                \
      STG_B(NX, 0, kn1);                                                        \
      VMC4();                                                                   \
    } else {                                                                    \
      VMC0();                                                                   \
    }                                                                           \
    BARF();                                                                     \
    MFMA_QUAD(4, af2);                                                          \
    BARF();                                                                     \
    /* P2: all kh1 reads; stage A(t+1,k1) */                                    \
    _Pragma("unroll") for (int i = 0; i < 4; ++i)                               \
        af[i] = *(const f16x8*)&sA[CUR][1][aoff + i * 512];                     \
    _Pragma("unroll") for (int j = 0; j < 4; ++j)                               \
        bf[j] = *(const f16x8*)&sB[CUR][1][boff + j * 512];                     \
    _Pragma("unroll") for (int i = 0; i < 4; ++i)                               \
        af2[i] = *(const f16x8*)&sA[CUR][1][aoff + (4 + i) * 512];              \
    if (more1) { STG_A(NX, 1, kn1 + 32); }                                      \
    BARF();                                                                     \
    MFMA_QUAD(0, af);                                                           \
    BARF();                                                                     \
    /* P3: stage B(t+1,k1); EARLY gate kh0(t+1); MFMA kh1 m4-7 */               \
    if (more1) {                                                                \
      STG_B(NX, 1, kn1 + 32);                                                   \
      VMC4();                                                                   \
    }                                                                           \
    BARF();                                                                     \
    MFMA_QUAD(4, af2);                                                          \
    BARF();                                                                     \
  }

template <bool OUT_F16, bool SWZ>
__global__ __launch_bounds__(512, 2) void gemm256(const _Float16* __restrict__ A,
                                                  const _Float16* __restrict__ B,
                                                  void* __restrict__ C,
                                                  const float* __restrict__ bias,
                                                  const float* __restrict__ scale,
                                                  int N, int K) {
  __shared__ _Float16 sA[2][2][8192];  // [buf][khalf][16 frag * 512] = 64KB
  __shared__ _Float16 sB[2][2][8192];  // 64KB

  const int tid = threadIdx.x;
  const int lane = tid & 63;
  const int wave = tid >> 6;
  const int wm = wave >> 2;  // 0..1 -> C rows wm*128..+128
  const int wn = wave & 3;   // 0..3 -> C cols wn*64..+64

  // T1 chunked XCD swizzle, per-GEMM (G2 only: gx=8 => xcd==bx pathology).
  int bx, by;
  if constexpr (SWZ) {
    const int gx = gridDim.x;
    const int nwg = gx * gridDim.y;
    const int hw = blockIdx.y * gx + blockIdx.x;
    const int logical = (hw & 7) * (nwg >> 3) + (hw >> 3);
    bx = logical % gx;
    by = logical / gx;
  } else {
    bx = blockIdx.x;
    by = blockIdx.y;
  }
  const long row0 = (long)by * 256;
  const long col0 = (long)bx * 256;

  // Staging: chunk c in [0,1024): frag mb=c>>6, row=mb*16+(c&15), koct=(c>>4)&3.
  const int c0 = tid, c1 = tid + 512;
  const _Float16* pA0 = A + (row0 + ((c0 >> 6) << 4) + (c0 & 15)) * (long)K + (((c0 >> 4) & 3) << 3);
  const _Float16* pA1 = A + (row0 + ((c1 >> 6) << 4) + (c1 & 15)) * (long)K + (((c1 >> 4) & 3) << 3);
  const _Float16* pB0 = B + (col0 + ((c0 >> 6) << 4) + (c0 & 15)) * (long)K + (((c0 >> 4) & 3) << 3);
  const _Float16* pB1 = B + (col0 + ((c1 >> 6) << 4) + (c1 & 15)) * (long)K + (((c1 >> 4) & 3) << 3);

  f32x4 acc[8][4] = {};
  const int nT = K >> 6;  // 32 (G1) or 128 (G2): always even
  const int aoff = wm * 8 * 512 + lane * 8;  // elems; frag mf adds mf*512
  const int boff = wn * 4 * 512 + lane * 8;

  // Prologue: tile 0 -> buf 0; certify kh0 (leaves A/B(0,k1) outstanding).
  STG_A(0, 0, 0);
  STG_B(0, 0, 0);
  STG_A(0, 1, 32);
  STG_B(0, 1, 32);
  VMC4();
  BARF();

  // x2 unroll: CUR/NX are literals -> static LDS bases + immediate offsets.
  for (int tt = 0; tt < nT; tt += 2) {
    TILE_BODY(0, 1, tt);
    TILE_BODY(1, 0, tt + 1);
  }

  // Epilogue: C/D layout col = lane&15, row = (lane>>4)*4 + reg.
  const int qd = lane >> 4, l16 = lane & 15;
#pragma unroll
  for (int nf = 0; nf < 4; ++nf) {
    const long c = col0 + wn * 64 + nf * 16 + l16;
    const float bb = bias[c];
    const float ss = scale[c];
#pragma unroll
    for (int mf = 0; mf < 8; ++mf) {
      const long r = row0 + wm * 128 + mf * 16 + qd * 4;
#pragma unroll
      for (int reg = 0; reg < 4; ++reg) {
        const float v = (acc[mf][nf][reg] + bb) * ss;
        if constexpr (OUT_F16)
          ((_Float16*)C)[(r + reg) * (long)N + c] = (_Float16)v;
        else
          ((float*)C)[(r + reg) * (long)N + c] = v;
      }
    }
  }
}

// ---------------- row LayerNorm kernels ----------------

// D = 8192, f16 in/out, LN*g+b then relu, in place. One block (256 thr) per row.
__global__ __launch_bounds__(256) void ln_relu_rows_f16(_Float16* __restrict__ h,
                                                        const float* __restrict__ g,
                                                        const float* __restrict__ b) {
  const int D = 8192;
  const long base = (long)blockIdx.x * D;
  const int tid = threadIdx.x;
  f16x8 v[4];
  float sum = 0.f, sq = 0.f;
#pragma unroll
  for (int c = 0; c < 4; ++c) {
    v[c] = *(const f16x8*)&h[base + c * 2048 + tid * 8];
#pragma unroll
    for (int e = 0; e < 8; ++e) {
      const float f = (float)v[c][e];
      sum += f;
      sq += f * f;
    }
  }
#pragma unroll
  for (int off = 32; off > 0; off >>= 1) {
    sum += __shfl_down(sum, off);
    sq += __shfl_down(sq, off);
  }
  __shared__ float rs[4], rq[4];
  const int wv = tid >> 6, ln = tid & 63;
  if (ln == 0) { rs[wv] = sum; rq[wv] = sq; }
  __syncthreads();
  sum = rs[0] + rs[1] + rs[2] + rs[3];
  sq = rq[0] + rq[1] + rq[2] + rq[3];
  const float mu = sum / D;
  const float rstd = rsqrtf(sq / D - mu * mu + LN_EPS);
#pragma unroll
  for (int c = 0; c < 4; ++c) {
    const int col = c * 2048 + tid * 8;
    f16x8 o;
#pragma unroll
    for (int e = 0; e < 8; ++e) {
      const float f = ((float)v[c][e] - mu) * rstd * g[col + e] + b[col + e];
      o[e] = (_Float16)fmaxf(f, 0.f);
    }
    *(f16x8*)&h[base + col] = o;
  }
}

// D = 2048, f32, LN*g+b IN PLACE on d_out. One block (256 thr) per row.
__global__ __launch_bounds__(256) void ln_rows_f32_inplace(float* __restrict__ io,
                                                           const float* __restrict__ g,
                                                           const float* __restrict__ b) {
  const int D = 2048;
  const long base = (long)blockIdx.x * D;
  const int tid = threadIdx.x;
  const float4 v0 = *(const float4*)&io[base + tid * 8];
  const float4 v1 = *(const float4*)&io[base + tid * 8 + 4];
  const float a[8] = {v0.x, v0.y, v0.z, v0.w, v1.x, v1.y, v1.z, v1.w};
  float sum = 0.f, sq = 0.f;
#pragma unroll
  for (int e = 0; e < 8; ++e) {
    sum += a[e];
    sq += a[e] * a[e];
  }
#pragma unroll
  for (int off = 32; off > 0; off >>= 1) {
    sum += __shfl_down(sum, off);
    sq += __shfl_down(sq, off);
  }
  __shared__ float rs[4], rq[4];
  const int wv = tid >> 6, ln = tid & 63;
  if (ln == 0) { rs[wv] = sum; rq[wv] = sq; }
  __syncthreads();
  sum = rs[0] + rs[1] + rs[2] + rs[3];
  sq = rq[0] + rq[1] + rq[2] + rq[3];
  const float mu = sum / D;
  const float rstd = rsqrtf(sq / D - mu * mu + LN_EPS);
  const int col = tid * 8;
  float o[8];
#pragma unroll
  for (int e = 0; e < 8; ++e) o[e] = (a[e] - mu) * rstd * g[col + e] + b[col + e];
  *(float4*)&io[base + col] = make_float4(o[0], o[1], o[2], o[3]);
  *(float4*)&io[base + col + 4] = make_float4(o[4], o[5], o[6], o[7]);
}

// ---------------- launch ----------------

extern "C" void kernel_launch(void* const* d_in, const int* in_sizes, int n_in,
                              void* d_out, int out_size, void* d_ws, size_t ws_size,
                              hipStream_t stream) {
  const float* x    = (const float*)d_in[0];
  const float* w1   = (const float*)d_in[1];
  const float* b1   = (const float*)d_in[2];
  const float* s1   = (const float*)d_in[3];
  const float* w2   = (const float*)d_in[4];
  const float* b2   = (const float*)d_in[5];
  const float* s2   = (const float*)d_in[6];
  const float* ln1g = (const float*)d_in[7];
  const float* ln1b = (const float*)d_in[8];
  const float* outg = (const float*)d_in[9];
  const float* outb = (const float*)d_in[10];

  const int N = 8192, D_IN = 2048, D_H = 8192, D_OUT = 2048;
  const size_t MB = 1024 * 1024;
  // Scratch phase-1 buffers live in d_out (64MB); dead before GEMM2 writes it.
  char* ob = (char*)d_out;
  _Float16* xh  = (_Float16*)(ob);            // 32MB
  _Float16* tw1 = (_Float16*)(ob + 32 * MB);  // 32MB
  // Persistent-through-GEMM2 buffers in d_ws (160MB used).
  char* ws = (char*)d_ws;
  _Float16* tw2 = (_Float16*)(ws);            // 32MB
  _Float16* h   = (_Float16*)(ws + 32 * MB);  // 128MB

  // elementwise prep: each block handles 2048 elems
  cvt_x_f16<<<(N * D_IN) / 2048, 256, 0, stream>>>(x, xh);
  quant_w<<<(D_H * D_IN) / 2048, 256, 0, stream>>>(w1, tw1);
  quant_w<<<(D_OUT * D_H) / 2048, 256, 0, stream>>>(w2, tw2);

  // layer 1: h = (x @ tw1^T + b1) * s1   -> f16  (no swizzle: natural raster wins)
  gemm256<true, false><<<dim3(D_H / 256, N / 256), 512, 0, stream>>>(xh, tw1, h, b1, s1, D_H, D_IN);
  // LN + relu in place
  ln_relu_rows_f16<<<N, 256, 0, stream>>>(h, ln1g, ln1b);

  // layer 2: (h @ tw2^T + b2) * s2 -> f32, straight into d_out (xh/tw1 dead)
  // swizzle ON: gx=8 natural order puts each column on one XCD (A refetch 8x)
  gemm256<false, true><<<dim3(D_OUT / 256, N / 256), 512, 0, stream>>>(h, tw2, d_out, b2, s2, D_OUT, D_H);
  // final LN in place on d_out
  ln_rows_f32_inplace<<<N, 256, 0, stream>>>((float*)d_out, outg, outb);
}

// Round 7
// 881.658 us; speedup vs baseline: 1.2904x; 1.1025x over previous
//
#include <hip/hip_runtime.h>

// LowBitMLP on MI355X (gfx950).
// R9: revert R8 unroll (cost +43us on G1: VGPR 100->128, sched worse); back
//     to EXACT R5 loop body (early gates, af2-preread, dynamic cur) which
//     measured G1=350us. Keep per-GEMM swizzle (G1 off / G2 on).
// NEW (a): LDS-bounce epilogue. R8 G1: WRITE=310MB vs 128 ideal; ~130MB of
//     FETCH is RMW of partial 32B-of-128B line stores. Each wave transposes
//     its 16x64 row-block via private padded LDS scratch (scatter b16/b32
//     writes, stride 72/68 to spread banks; coalesced b128 reads), stores
//     full 128-256B row segments. Wave-private + per-wave in-order DS =>
//     no barriers. sA is dead after the K-loop's final barrier.
// NEW (b): fuse the 3 prep kernels into 1 (block-uniform segment switch).
// Ledger (unchanged from R5, verified): stages A(t+1,k0)@P0 B(t+1,k0)@P1
//   A(t+1,k1)@P2 B(t+1,k1)@P3 (2 ops each); gate@P1 after STG_B: vmcnt(4)
//   certifies A/B(t,k1) (newer=A/B(t+1,k0)); gate@P3: vmcnt(4) certifies
//   A/B(t+1,k0) (newer=A/B(t+1,k1)); tail t=nT-1: VMC0 at P1, no stages.
//
// Memory plan (unchanged):
//   d_out: [0,32M) x_h f16; [32M,64M) tw1 f16   (dead before GEMM2 writes)
//   d_ws : [0,32M) tw2 f16; [32M,160M) h f16 (GEMM1 out, LN1+relu in place)

#define THRESH 0.1f
#define LN_EPS 1e-5f

typedef _Float16 f16x8 __attribute__((ext_vector_type(8)));
typedef float f32x4 __attribute__((ext_vector_type(4)));

typedef __attribute__((address_space(3))) void lds_void;
typedef const __attribute__((address_space(1))) void glob_void;

__device__ __forceinline__ void gld16(const void* g, void* l) {
  __builtin_amdgcn_global_load_lds((glob_void*)g, (lds_void*)l, 16, 0, 0);
}

// ---------------- fused elementwise prep (1 launch, 3 segments) ----------------
// seg 0: cast x -> f16. seg 1/2: ternary quant w1/w2 -> f16. 8 elems/thread.

__global__ __launch_bounds__(256) void prep_fused(const float* __restrict__ x,
                                                  const float* __restrict__ w1,
                                                  const float* __restrict__ w2,
                                                  _Float16* __restrict__ xh,
                                                  _Float16* __restrict__ tw1,
                                                  _Float16* __restrict__ tw2) {
  const int seg = blockIdx.x >> 13;  // 8192 blocks per 16.7M-elem segment
  const long i = ((long)(blockIdx.x & 8191) * 256 + threadIdx.x) * 8;
  const float* src = (seg == 0) ? x : (seg == 1) ? w1 : w2;
  _Float16* dst = (seg == 0) ? xh : (seg == 1) ? tw1 : tw2;
  const float4 v0 = *(const float4*)(src + i);
  const float4 v1 = *(const float4*)(src + i + 4);
  const float a[8] = {v0.x, v0.y, v0.z, v0.w, v1.x, v1.y, v1.z, v1.w};
  f16x8 o;
  if (seg == 0) {
#pragma unroll
    for (int e = 0; e < 8; ++e) o[e] = (_Float16)a[e];
  } else {
#pragma unroll
    for (int e = 0; e < 8; ++e) {
      const float q = (fabsf(a[e]) < THRESH) ? 0.f : (a[e] > 0.f ? 1.f : -1.f);
      o[e] = (_Float16)q;
    }
  }
  *(f16x8*)(dst + i) = o;
}

// ---------------- 256^2 8-phase GEMM-BT: C = A(MxK) * B(NxK)^T, fused (acc+b)*s --------
// LDS layout: per buffer, per k-half, 16 fragment blocks of 16rows x 32k
// (1KB each, fragment-contiguous => conflict-free ds_read_b128; staging dest
// is linear chunk index => satisfies global_load_lds wave-uniform+lane*16).

#define BARF()                       \
  __builtin_amdgcn_s_barrier();      \
  asm volatile("" ::: "memory")
#define VMC4() asm volatile("s_waitcnt vmcnt(4)" ::: "memory")
#define VMC0() asm volatile("s_waitcnt vmcnt(0)" ::: "memory")

#define MFMA_QUAD(m0, AF)                                                                    \
  __builtin_amdgcn_s_setprio(1);                                                             \
  _Pragma("unroll") for (int i = 0; i < 4; ++i)                                              \
  _Pragma("unroll") for (int j = 0; j < 4; ++j)                                              \
      acc[(m0) + i][j] = __builtin_amdgcn_mfma_f32_16x16x32_f16(AF[i], bf[j],                \
                                                                acc[(m0) + i][j], 0, 0, 0); \
  __builtin_amdgcn_s_setprio(0)

template <bool OUT_F16, bool SWZ>
__global__ __launch_bounds__(512, 2) void gemm256(const _Float16* __restrict__ A,
                                                  const _Float16* __restrict__ B,
                                                  void* __restrict__ C,
                                                  const float* __restrict__ bias,
                                                  const float* __restrict__ scale,
                                                  int N, int K) {
  __shared__ _Float16 sA[2][2][8192];  // [buf][khalf][16 frag * 512] = 64KB
  __shared__ _Float16 sB[2][2][8192];  // 64KB

  const int tid = threadIdx.x;
  const int lane = tid & 63;
  const int wave = tid >> 6;
  const int wm = wave >> 2;  // 0..1 -> C rows wm*128..+128
  const int wn = wave & 3;   // 0..3 -> C cols wn*64..+64

  // T1 chunked XCD swizzle, per-GEMM (G2 only: gx=8 => xcd==bx pathology).
  int bx, by;
  if constexpr (SWZ) {
    const int gx = gridDim.x;
    const int nwg = gx * gridDim.y;
    const int hw = blockIdx.y * gx + blockIdx.x;
    const int logical = (hw & 7) * (nwg >> 3) + (hw >> 3);
    bx = logical % gx;
    by = logical / gx;
  } else {
    bx = blockIdx.x;
    by = blockIdx.y;
  }
  const long row0 = (long)by * 256;
  const long col0 = (long)bx * 256;

  // Staging: chunk c in [0,1024): frag mb=c>>6, row=mb*16+(c&15), koct=(c>>4)&3.
  const int c0 = tid, c1 = tid + 512;
  const _Float16* pA0 = A + (row0 + ((c0 >> 6) << 4) + (c0 & 15)) * (long)K + (((c0 >> 4) & 3) << 3);
  const _Float16* pA1 = A + (row0 + ((c1 >> 6) << 4) + (c1 & 15)) * (long)K + (((c1 >> 4) & 3) << 3);
  const _Float16* pB0 = B + (col0 + ((c0 >> 6) << 4) + (c0 & 15)) * (long)K + (((c0 >> 4) & 3) << 3);
  const _Float16* pB1 = B + (col0 + ((c1 >> 6) << 4) + (c1 & 15)) * (long)K + (((c1 >> 4) & 3) << 3);

#define STG_A(nx, kh, koff)                     \
  gld16(pA0 + (koff), &sA[nx][kh][c0 * 8]);     \
  gld16(pA1 + (koff), &sA[nx][kh][c1 * 8])
#define STG_B(nx, kh, koff)                     \
  gld16(pB0 + (koff), &sB[nx][kh][c0 * 8]);     \
  gld16(pB1 + (koff), &sB[nx][kh][c1 * 8])

  f32x4 acc[8][4] = {};
  const int nT = K >> 6;
  const int aoff = wm * 8 * 512 + lane * 8;  // elems; frag mf adds mf*512
  const int boff = wn * 4 * 512 + lane * 8;

  // Prologue: tile 0 -> buf 0; certify kh0 (leaves A/B(0,k1) outstanding).
  STG_A(0, 0, 0);
  STG_B(0, 0, 0);
  STG_A(0, 1, 32);
  STG_B(0, 1, 32);
  VMC4();
  BARF();

  for (int t = 0; t < nT; ++t) {
    const int cur = t & 1, nx = cur ^ 1;
    const bool more1 = (t + 1 < nT);
    const int kn1 = (t + 1) << 6;  // elems along K for tile t+1

    f16x8 af[4], af2[4], bf[4];

    // ---- P0: issue ALL kh0 reads (af0-3, bf, af4-7); stage A(t+1,k0) ----
#pragma unroll
    for (int i = 0; i < 4; ++i) af[i] = *(const f16x8*)&sA[cur][0][aoff + i * 512];
#pragma unroll
    for (int j = 0; j < 4; ++j) bf[j] = *(const f16x8*)&sB[cur][0][boff + j * 512];
#pragma unroll
    for (int i = 0; i < 4; ++i) af2[i] = *(const f16x8*)&sA[cur][0][aoff + (4 + i) * 512];
    if (more1) { STG_A(nx, 0, kn1); }
    BARF();
    MFMA_QUAD(0, af);  // compiler emits counted lgkmcnt: af2 still in flight
    BARF();

    // ---- P1: stage B(t+1,k0); EARLY gate kh1(t); MFMA kh0 m4-7 ----
    if (more1) {
      STG_B(nx, 0, kn1);
      VMC4();  // A/B(t,k1) landed; newer = A/B(t+1,k0)
    } else {
      VMC0();  // last tile: only A/B(t,k1) outstanding
    }
    BARF();
    MFMA_QUAD(4, af2);
    BARF();

    // ---- P2: issue ALL kh1 reads; stage A(t+1,k1) ----
#pragma unroll
    for (int i = 0; i < 4; ++i) af[i] = *(const f16x8*)&sA[cur][1][aoff + i * 512];
#pragma unroll
    for (int j = 0; j < 4; ++j) bf[j] = *(const f16x8*)&sB[cur][1][boff + j * 512];
#pragma unroll
    for (int i = 0; i < 4; ++i) af2[i] = *(const f16x8*)&sA[cur][1][aoff + (4 + i) * 512];
    if (more1) { STG_A(nx, 1, kn1 + 32); }
    BARF();
    MFMA_QUAD(0, af);
    BARF();

    // ---- P3: stage B(t+1,k1); EARLY gate kh0(t+1); MFMA kh1 m4-7 ----
    if (more1) {
      STG_B(nx, 1, kn1 + 32);
      VMC4();  // A/B(t+1,k0) landed; newer = A/B(t+1,k1)
    }
    BARF();
    MFMA_QUAD(4, af2);
    BARF();
  }

  // ---- Epilogue: LDS-bounce to full-line coalesced stores. ----
  // After the loop's final BARF all LDS reads are done => sA reusable.
  // Wave-private scratch; per-wave in-order DS => no barriers.
  // MFMA C/D: col = lane&15, row = (lane>>4)*4 + reg (per 16x16 frag).
  const int qd = lane >> 4, l16 = lane & 15;
  float bb[4], ss[4];
#pragma unroll
  for (int nf = 0; nf < 4; ++nf) {
    const long c = col0 + wn * 64 + nf * 16 + l16;
    bb[nf] = bias[c];
    ss[nf] = scale[c];
  }

  if constexpr (OUT_F16) {
    // 16 rows x 64 cols f16 per mf-block; row stride 72 (144B, 16B-mult,
    // spreads scatter-writes over 16 banks => <=4-way).
    _Float16* wbuf = (_Float16*)&sA[0][0][0] + wave * (16 * 72);
#pragma unroll
    for (int mf = 0; mf < 8; ++mf) {
#pragma unroll
      for (int nf = 0; nf < 4; ++nf)
#pragma unroll
        for (int reg = 0; reg < 4; ++reg)
          wbuf[(qd * 4 + reg) * 72 + nf * 16 + l16] =
              (_Float16)((acc[mf][nf][reg] + bb[nf]) * ss[nf]);
      // read row l16, cols qd*16..+15 (32B) -> store full 128B/row per wave
      const f16x8 r0 = *(const f16x8*)&wbuf[l16 * 72 + qd * 16];
      const f16x8 r1 = *(const f16x8*)&wbuf[l16 * 72 + qd * 16 + 8];
      const long r = row0 + wm * 128 + mf * 16 + l16;
      _Float16* gp = (_Float16*)C + r * (long)N + col0 + wn * 64 + qd * 16;
      *(f16x8*)gp = r0;
      *(f16x8*)(gp + 8) = r1;
    }
  } else {
    // 16 rows x 64 cols f32; row stride 68 (272B, 16B-mult).
    float* wbuf = (float*)&sA[0][0][0] + wave * (16 * 68);
#pragma unroll
    for (int mf = 0; mf < 8; ++mf) {
#pragma unroll
      for (int nf = 0; nf < 4; ++nf)
#pragma unroll
        for (int reg = 0; reg < 4; ++reg)
          wbuf[(qd * 4 + reg) * 68 + nf * 16 + l16] =
              (acc[mf][nf][reg] + bb[nf]) * ss[nf];
      const long r = row0 + wm * 128 + mf * 16 + l16;
      float* gp = (float*)C + r * (long)N + col0 + wn * 64 + qd * 16;
#pragma unroll
      for (int j = 0; j < 4; ++j)
        *(float4*)(gp + j * 4) = *(const float4*)&wbuf[l16 * 68 + qd * 16 + j * 4];
    }
  }
}

// ---------------- row LayerNorm kernels ----------------

// D = 8192, f16 in/out, LN*g+b then relu, in place. One block (256 thr) per row.
__global__ __launch_bounds__(256) void ln_relu_rows_f16(_Float16* __restrict__ h,
                                                        const float* __restrict__ g,
                                                        const float* __restrict__ b) {
  const int D = 8192;
  const long base = (long)blockIdx.x * D;
  const int tid = threadIdx.x;
  f16x8 v[4];
  float sum = 0.f, sq = 0.f;
#pragma unroll
  for (int c = 0; c < 4; ++c) {
    v[c] = *(const f16x8*)&h[base + c * 2048 + tid * 8];
#pragma unroll
    for (int e = 0; e < 8; ++e) {
      const float f = (float)v[c][e];
      sum += f;
      sq += f * f;
    }
  }
#pragma unroll
  for (int off = 32; off > 0; off >>= 1) {
    sum += __shfl_down(sum, off);
    sq += __shfl_down(sq, off);
  }
  __shared__ float rs[4], rq[4];
  const int wv = tid >> 6, ln = tid & 63;
  if (ln == 0) { rs[wv] = sum; rq[wv] = sq; }
  __syncthreads();
  sum = rs[0] + rs[1] + rs[2] + rs[3];
  sq = rq[0] + rq[1] + rq[2] + rq[3];
  const float mu = sum / D;
  const float rstd = rsqrtf(sq / D - mu * mu + LN_EPS);
#pragma unroll
  for (int c = 0; c < 4; ++c) {
    const int col = c * 2048 + tid * 8;
    f16x8 o;
#pragma unroll
    for (int e = 0; e < 8; ++e) {
      const float f = ((float)v[c][e] - mu) * rstd * g[col + e] + b[col + e];
      o[e] = (_Float16)fmaxf(f, 0.f);
    }
    *(f16x8*)&h[base + col] = o;
  }
}

// D = 2048, f32, LN*g+b IN PLACE on d_out. One block (256 thr) per row.
__global__ __launch_bounds__(256) void ln_rows_f32_inplace(float* __restrict__ io,
                                                           const float* __restrict__ g,
                                                           const float* __restrict__ b) {
  const int D = 2048;
  const long base = (long)blockIdx.x * D;
  const int tid = threadIdx.x;
  const float4 v0 = *(const float4*)&io[base + tid * 8];
  const float4 v1 = *(const float4*)&io[base + tid * 8 + 4];
  const float a[8] = {v0.x, v0.y, v0.z, v0.w, v1.x, v1.y, v1.z, v1.w};
  float sum = 0.f, sq = 0.f;
#pragma unroll
  for (int e = 0; e < 8; ++e) {
    sum += a[e];
    sq += a[e] * a[e];
  }
#pragma unroll
  for (int off = 32; off > 0; off >>= 1) {
    sum += __shfl_down(sum, off);
    sq += __shfl_down(sq, off);
  }
  __shared__ float rs[4], rq[4];
  const int wv = tid >> 6, ln = tid & 63;
  if (ln == 0) { rs[wv] = sum; rq[wv] = sq; }
  __syncthreads();
  sum = rs[0] + rs[1] + rs[2] + rs[3];
  sq = rq[0] + rq[1] + rq[2] + rq[3];
  const float mu = sum / D;
  const float rstd = rsqrtf(sq / D - mu * mu + LN_EPS);
  const int col = tid * 8;
  float o[8];
#pragma unroll
  for (int e = 0; e < 8; ++e) o[e] = (a[e] - mu) * rstd * g[col + e] + b[col + e];
  *(float4*)&io[base + col] = make_float4(o[0], o[1], o[2], o[3]);
  *(float4*)&io[base + col + 4] = make_float4(o[4], o[5], o[6], o[7]);
}

// ---------------- launch ----------------

extern "C" void kernel_launch(void* const* d_in, const int* in_sizes, int n_in,
                              void* d_out, int out_size, void* d_ws, size_t ws_size,
                              hipStream_t stream) {
  const float* x    = (const float*)d_in[0];
  const float* w1   = (const float*)d_in[1];
  const float* b1   = (const float*)d_in[2];
  const float* s1   = (const float*)d_in[3];
  const float* w2   = (const float*)d_in[4];
  const float* b2   = (const float*)d_in[5];
  const float* s2   = (const float*)d_in[6];
  const float* ln1g = (const float*)d_in[7];
  const float* ln1b = (const float*)d_in[8];
  const float* outg = (const float*)d_in[9];
  const float* outb = (const float*)d_in[10];

  const int N = 8192, D_IN = 2048, D_H = 8192, D_OUT = 2048;
  const size_t MB = 1024 * 1024;
  // Scratch phase-1 buffers live in d_out (64MB); dead before GEMM2 writes it.
  char* ob = (char*)d_out;
  _Float16* xh  = (_Float16*)(ob);            // 32MB
  _Float16* tw1 = (_Float16*)(ob + 32 * MB);  // 32MB
  // Persistent-through-GEMM2 buffers in d_ws (160MB used).
  char* ws = (char*)d_ws;
  _Float16* tw2 = (_Float16*)(ws);            // 32MB
  _Float16* h   = (_Float16*)(ws + 32 * MB);  // 128MB

  // fused elementwise prep: 3 segments x 8192 blocks, 2048 elems/block
  prep_fused<<<3 * 8192, 256, 0, stream>>>(x, w1, w2, xh, tw1, tw2);

  // layer 1: h = (x @ tw1^T + b1) * s1   -> f16  (no swizzle: natural raster wins)
  gemm256<true, false><<<dim3(D_H / 256, N / 256), 512, 0, stream>>>(xh, tw1, h, b1, s1, D_H, D_IN);
  // LN + relu in place
  ln_relu_rows_f16<<<N, 256, 0, stream>>>(h, ln1g, ln1b);

  // layer 2: (h @ tw2^T + b2) * s2 -> f32, straight into d_out (xh/tw1 dead)
  // swizzle ON: gx=8 natural order puts each column on one XCD (A refetch 8x)
  gemm256<false, true><<<dim3(D_OUT / 256, N / 256), 512, 0, stream>>>(h, tw2, d_out, b2, s2, D_OUT, D_H);
  // final LN in place on d_out
  ln_rows_f32_inplace<<<N, 256, 0, stream>>>((float*)d_out, outg, outb);
}